// Round 23
// baseline (472.397 us; speedup 1.0000x reference)
//
#include <hip/hip_runtime.h>
#include <hip/hip_fp16.h>

#define NNODES 200000
#define NEDGES 6400000
#define NENT   2048
#define CH     8
#define HID    32
#define NCONV  8
#define BN_EPS 1e-5f

#define BSZ    196                                  // nodes per dst-bucket
#define NBUCK  1024                                 // 1024 buckets -> exactly 4 blocks/CU
#define SRCB   391                                  // src bins (src>>9)
#define CHUNK  4096
#define NCHUNK ((NEDGES + CHUNK - 1) / CHUNK)       // 1563
#define SPAD   16                                   // one 64B line per stat-copy
#define SCOP   16                                   // stat copies (bounds same-line atomic serialization)
#define SUBCAP 8192                                 // staged edges per bucket (32 KB; run ~6272)
#define ESTG   512                                  // k_push edge stage size (64 groups x 8 edges)
#define ACCS   8                                    // acc stride

#define I16SCALE  2048.0f                           // 2^11 fixed-point scale for int16 hts
#define I16INV    (1.0f/2048.0f)

// stats slot layout: [stat t (0..15)][copy c (0..15)] each on its own 64B line
#define SSLOT  (2*CH*SCOP*SPAD)                     // floats per layer slot (4096)

__device__ __forceinline__ int bucket_of(int d){ return (int)((unsigned)d / 196u); }

// bijective XCD-chunked swizzle (m204 form): consecutive work-ids land on one XCD
__device__ __forceinline__ int xcd_swz(int bid, int nwg){
  int xcd = bid & 7, idx = bid >> 3;
  int q = nwg >> 3, r = nwg & 7;
  return (xcd < r ? xcd*(q+1) : r*(q+1) + (xcd-r)*q) + idx;
}

// ---------------- phase A: per-chunk bucket histogram ----------------
__global__ __launch_bounds__(256) void k_chist(const int* __restrict__ dst, int* __restrict__ cnt, int E){
  __shared__ int hist[NBUCK];
  for(int t=threadIdx.x; t<NBUCK; t+=256) hist[t]=0;
  __syncthreads();
  int e0 = blockIdx.x*CHUNK;
  int n = min(CHUNK, E-e0);
  for(int i=threadIdx.x; i<n; i+=256) atomicAdd(&hist[bucket_of(dst[e0+i])], 1);
  __syncthreads();
  for(int t=threadIdx.x; t<NBUCK; t+=256) cnt[(size_t)blockIdx.x*NBUCK + t] = hist[t];
}

// ---------------- phase B1: per-bucket exclusive scan over chunks (XCD-swizzled) ----------------
__global__ __launch_bounds__(256) void k_cscan(int* __restrict__ cnt, int* __restrict__ total){
  int b = xcd_swz(blockIdx.x, NBUCK);     // adjacent buckets on same XCD -> shared lines merge
  __shared__ int sd[256];
  int carry = 0;
  for(int base=0; base<NCHUNK; base+=256){
    int c = base + threadIdx.x;
    int v = (c<NCHUNK) ? cnt[(size_t)c*NBUCK + b] : 0;
    sd[threadIdx.x] = v; __syncthreads();
    #pragma unroll
    for(int o=1; o<256; o<<=1){
      int x = (threadIdx.x>=o) ? sd[threadIdx.x-o] : 0;
      __syncthreads();
      sd[threadIdx.x] += x;
      __syncthreads();
    }
    if(c<NCHUNK) cnt[(size_t)c*NBUCK + b] = carry + sd[threadIdx.x] - v;  // exclusive
    carry += sd[255];
    __syncthreads();
  }
  if(threadIdx.x==0) total[b] = carry;
}

// ---------------- phase B2: bucket base scan (1024 bins, 1024 threads) ----------------
__global__ __launch_bounds__(1024) void k_bscan(const int* __restrict__ total, int* __restrict__ bbase){
  __shared__ int sd[1024];
  int t = threadIdx.x;
  int v = total[t];
  sd[t] = v; __syncthreads();
  #pragma unroll
  for(int o=1; o<1024; o<<=1){
    int x = (t>=o) ? sd[t-o] : 0;
    __syncthreads();
    sd[t] += x;
    __syncthreads();
  }
  bbase[t] = sd[t] - v;
  if(t==1023) bbase[NBUCK] = sd[1023];   // == NEDGES
}

// ---------------- phase C: LDS counting-sort scatter into bucket runs ----------------
// packed edge = (dst_local<<18) | src   (src<2^18, dst_local<196)
__global__ __launch_bounds__(1024) void k_bin(const int* __restrict__ src, const int* __restrict__ dst,
                                              const int* __restrict__ cnt, const int* __restrict__ total,
                                              const int* __restrict__ bbase,
                                              unsigned int* __restrict__ binned, int E){
  __shared__ int excl[NBUCK], cur[NBUCK], base[NBUCK];
  __shared__ unsigned int pin[CHUNK];
  __shared__ unsigned short bk_in[CHUNK];
  __shared__ unsigned int sorted[CHUNK];
  __shared__ unsigned short sbkt[CHUNK];
  __shared__ int sd[1024];
  int c = xcd_swz(blockIdx.x, NCHUNK);
  int e0 = c*CHUNK, n = min(CHUNK, E-e0);
  int t = threadIdx.x;
  for(int i=t; i<n; i+=1024){
    int s = src[e0+i], d = dst[e0+i];
    int b = bucket_of(d);
    pin[i]   = ((unsigned)(d - b*BSZ)<<18) | (unsigned)s;
    bk_in[i] = (unsigned short)b;
  }
  int h0 = cnt[(size_t)c*NBUCK + t];
  int h1 = (c+1 < NCHUNK) ? cnt[(size_t)(c+1)*NBUCK + t] : total[t];
  int hv = h1 - h0;                        // this chunk's count for bucket t
  sd[t] = hv; __syncthreads();
  #pragma unroll
  for(int o=1; o<1024; o<<=1){
    int x = (t>=o) ? sd[t-o] : 0;
    __syncthreads();
    sd[t] += x;
    __syncthreads();
  }
  {
    int ex = sd[t] - hv;
    excl[t] = ex; cur[t] = ex;
    base[t] = bbase[t] + h0;
  }
  __syncthreads();
  for(int i=t; i<n; i+=1024){
    int b = bk_in[i];
    int slot = atomicAdd(&cur[b], 1);
    sorted[slot] = pin[i];
    sbkt[slot]   = (unsigned short)b;
  }
  __syncthreads();
  for(int i=t; i<n; i+=1024){
    int b = sbkt[i];
    binned[ base[b] + (i - excl[b]) ] = sorted[i];   // contiguous runs per bucket
  }
}

// ---------------- phase D: per-bucket SRC-BIN sort, LDS-staged coalesced output ----------------
__global__ __launch_bounds__(512) void k_sub(const unsigned int* __restrict__ binned,
                                             const int* __restrict__ bbase,
                                             unsigned int* __restrict__ binned2,
                                             float* __restrict__ dinv, int N){
  __shared__ int hd[BSZ];        // dst_local degree histogram
  __shared__ int hs[SRCB];       // src-bin histogram
  __shared__ int cur[SRCB];
  __shared__ int sd[512];
  __shared__ unsigned int stage[SUBCAP];   // 32 KB
  int b = blockIdx.x;
  int t = threadIdx.x;
  if(t < BSZ)  hd[t] = 0;
  if(t < SRCB) hs[t] = 0;
  __syncthreads();
  int s0 = bbase[b], s1 = bbase[b+1];
  for(int i=s0+t; i<s1; i+=512){
    unsigned p = binned[i];
    atomicAdd(&hd[p>>18], 1);
    atomicAdd(&hs[(p & 0x3FFFF)>>9], 1);
  }
  __syncthreads();
  if(t < BSZ){
    int node = b*BSZ + t;
    if(node < N) dinv[node] = 1.0f / sqrtf((float)hd[t] + 1.0f);
  }
  int hv = (t<SRCB) ? hs[t] : 0;
  sd[t] = hv; __syncthreads();
  #pragma unroll
  for(int o=1; o<512; o<<=1){
    int x = (t>=o) ? sd[t-o] : 0;
    __syncthreads();
    sd[t] += x;
    __syncthreads();
  }
  if(t<SRCB) cur[t] = sd[t] - hv;          // stage-relative
  __syncthreads();
  int len = s1 - s0;
  if(len <= SUBCAP){
    for(int i=s0+t; i<s1; i+=512){
      unsigned p = binned[i];
      int slot = atomicAdd(&cur[(p & 0x3FFFF)>>9], 1);
      stage[slot] = p;
    }
    __syncthreads();
    for(int i=t; i<len; i+=512) binned2[s0 + i] = stage[i];   // coalesced
  } else {                                 // degenerate fallback: direct scatter
    for(int i=s0+t; i<s1; i+=512){
      unsigned p = binned[i];
      int slot = atomicAdd(&cur[(p & 0x3FFFF)>>9], 1);
      binned2[s0 + slot] = p;
    }
  }
}

// ---------------- h init: embedding gather + stats[0] (multi-copy fp32 atomics) ----------------
__global__ __launch_bounds__(256) void k_init_h(const int* __restrict__ x, const float* __restrict__ emb,
                                                float* __restrict__ h, float* __restrict__ stats0, int N){
  int i = blockIdx.x*256 + threadIdx.x;
  float v[CH];
  #pragma unroll
  for(int c=0;c<CH;c++) v[c]=0.f;
  if(i < N){
    int tt = x[i];
    const float4* ep = (const float4*)(emb + (size_t)tt*CH);
    float4 a = ep[0], b = ep[1];
    float4* hp = (float4*)(h + (size_t)i*CH);
    hp[0] = a; hp[1] = b;
    v[0]=a.x; v[1]=a.y; v[2]=a.z; v[3]=a.w; v[4]=b.x; v[5]=b.y; v[6]=b.z; v[7]=b.w;
  }
  float s[CH], q[CH];
  #pragma unroll
  for(int c=0;c<CH;c++){ s[c]=v[c]; q[c]=v[c]*v[c]; }
  #pragma unroll
  for(int off=32; off>0; off>>=1){
    #pragma unroll
    for(int c=0;c<CH;c++){ s[c]+=__shfl_down(s[c],off); q[c]+=__shfl_down(q[c],off); }
  }
  __shared__ float ls[4][2*CH];
  int wave = threadIdx.x>>6, lane = threadIdx.x&63;
  if(lane==0){
    #pragma unroll
    for(int c=0;c<CH;c++){ ls[wave][c]=s[c]; ls[wave][CH+c]=q[c]; }
  }
  __syncthreads();
  if(threadIdx.x < 2*CH){
    float tsum = ls[0][threadIdx.x]+ls[1][threadIdx.x]+ls[2][threadIdx.x]+ls[3][threadIdx.x];
    unsafeAtomicAdd(&stats0[(threadIdx.x*SCOP + (blockIdx.x & (SCOP-1)))*SPAD], tsum);
  }
}

// ---------------- per-node transform: reduce stat copies, fold BN, hts = int16((h@A+c0)*dinv*2^11) ----------------
__global__ __launch_bounds__(256) void k_ht(const float* __restrict__ h, const float* __restrict__ stats_l,
                                            const float* __restrict__ gamma, const float* __restrict__ beta,
                                            const float* __restrict__ convw,
                                            const float* __restrict__ dinv,
                                            short* __restrict__ hts, int l, int N){
  __shared__ float A[CH*CH], c0[CH], sA[CH], sT[CH];
  int t = threadIdx.x;
  if(t < CH){
    float mu = 0.f, ex2 = 0.f;
    #pragma unroll
    for(int c=0;c<SCOP;c++){
      mu  += stats_l[((t   )*SCOP + c)*SPAD];
      ex2 += stats_l[((CH+t)*SCOP + c)*SPAD];
    }
    const float invN = 1.0f / (float)NNODES;
    mu *= invN; ex2 *= invN;
    float var = ex2 - mu*mu;
    float r   = 1.0f / sqrtf(var + BN_EPS);
    float sc  = r * gamma[l*CH+t];
    sA[t] = sc;
    sT[t] = beta[l*CH+t] - mu*sc;
  }
  __syncthreads();
  if(t < CH*CH){
    int ci = t>>3, co = t&7;
    A[t] = sA[ci] * convw[(l*CH+ci)*CH+co];
  }
  if(t < CH){
    float a = 0.f;
    #pragma unroll
    for(int ci=0;ci<CH;ci++) a += sT[ci]*convw[(l*CH+ci)*CH+t];
    c0[t] = a;
  }
  __syncthreads();
  int i = blockIdx.x*blockDim.x + threadIdx.x;
  if(i >= N) return;
  const float4* hp = (const float4*)(h + (size_t)i*CH);
  float4 a = hp[0], b = hp[1];
  float v[CH] = {a.x,a.y,a.z,a.w,b.x,b.y,b.z,b.w};
  float o[CH];
  #pragma unroll
  for(int co=0;co<CH;co++) o[co]=c0[co];
  #pragma unroll
  for(int ci=0;ci<CH;ci++){
    float vv = v[ci];
    #pragma unroll
    for(int co=0;co<CH;co++) o[co] += vv*A[ci*CH+co];
  }
  float dn = dinv[i] * I16SCALE;
  union { short ss[CH]; uint4 u; } pk;
  #pragma unroll
  for(int c=0;c<CH;c++){
    float val = fminf(fmaxf(o[c]*dn, -32767.f), 32767.f);
    pk.ss[c] = (short)__float2int_rn(val);
  }
  *(uint4*)(hts + (size_t)i*CH) = pk.u;
}

// ---------------- src-sorted bucket push + FUSED finalize (8-deep gather ILP) ----------------
// 1024 blocks (4/CU balanced), 512 threads = 64 groups x 8 lanes.
// Each group handles 8 edges per 512-edge window (one pass, no inner loop):
// 8 independent sext-short gathers in flight before the first LDS atomic.
__global__ __launch_bounds__(512) void k_push(const unsigned int* __restrict__ binned2,
                                              const int* __restrict__ bbase,
                                              const short* __restrict__ hts,
                                              const float* __restrict__ dinv,
                                              const float* __restrict__ convb,
                                              float* __restrict__ h, float* __restrict__ stats_next,
                                              int l, int N){
  __shared__ int acc[BSZ*ACCS];      // 6.1 KB, fixed-point 2^11
  __shared__ unsigned est[ESTG];     // 2 KB edge stage
  int b = blockIdx.x, t = threadIdx.x;
  for(int i=t; i<BSZ*ACCS; i+=512) acc[i] = 0;
  __syncthreads();
  int s0 = bbase[b], s1 = bbase[b+1];
  int lane8 = t & 7;
  int g = t >> 3;                          // 0..63
  int e0 = g*8;
  for(int off = s0; off < s1; off += ESTG){
    int n = min(ESTG, s1 - off);
    if(t < n) est[t] = binned2[off + t];   // coalesced
    __syncthreads();
    int m = n - e0;                        // edges for this group (<=8)
    if(m >= 8){
      unsigned p0=est[e0],   p1=est[e0+1], p2=est[e0+2], p3=est[e0+3];
      unsigned p4=est[e0+4], p5=est[e0+5], p6=est[e0+6], p7=est[e0+7];
      int v0 = (int)hts[(size_t)(p0 & 0x3FFFF)*CH + lane8];
      int v1 = (int)hts[(size_t)(p1 & 0x3FFFF)*CH + lane8];
      int v2 = (int)hts[(size_t)(p2 & 0x3FFFF)*CH + lane8];
      int v3 = (int)hts[(size_t)(p3 & 0x3FFFF)*CH + lane8];
      int v4 = (int)hts[(size_t)(p4 & 0x3FFFF)*CH + lane8];
      int v5 = (int)hts[(size_t)(p5 & 0x3FFFF)*CH + lane8];
      int v6 = (int)hts[(size_t)(p6 & 0x3FFFF)*CH + lane8];
      int v7 = (int)hts[(size_t)(p7 & 0x3FFFF)*CH + lane8];
      atomicAdd(&acc[(p0>>18)*ACCS + lane8], v0);
      atomicAdd(&acc[(p1>>18)*ACCS + lane8], v1);
      atomicAdd(&acc[(p2>>18)*ACCS + lane8], v2);
      atomicAdd(&acc[(p3>>18)*ACCS + lane8], v3);
      atomicAdd(&acc[(p4>>18)*ACCS + lane8], v4);
      atomicAdd(&acc[(p5>>18)*ACCS + lane8], v5);
      atomicAdd(&acc[(p6>>18)*ACCS + lane8], v6);
      atomicAdd(&acc[(p7>>18)*ACCS + lane8], v7);
    } else if(m > 0){
      for(int i=0; i<m; i++){
        unsigned p = est[e0+i];
        int v = (int)hts[(size_t)(p & 0x3FFFF)*CH + lane8];
        atomicAdd(&acc[(p>>18)*ACCS + lane8], v);
      }
    }
    __syncthreads();
  }
  // epilogue: thread t<BSZ owns node b*BSZ+t (this block exclusively owns these dsts)
  float vv[CH];
  #pragma unroll
  for(int c=0;c<CH;c++) vv[c]=0.f;
  int node = b*BSZ + t;
  if(t < BSZ && node < N){
    const int4* ar = (const int4*)(acc + t*ACCS);
    int4 a0 = ar[0], a1 = ar[1];
    float av[CH] = {(float)a0.x*I16INV,(float)a0.y*I16INV,(float)a0.z*I16INV,(float)a0.w*I16INV,
                    (float)a1.x*I16INV,(float)a1.y*I16INV,(float)a1.z*I16INV,(float)a1.w*I16INV};
    union { short ss[CH]; uint4 u; } su;
    su.u = *(const uint4*)(hts + (size_t)node*CH);          // self loop (pre-scaled)
    const float4* hp = (const float4*)(h + (size_t)node*CH);
    float4 h0 = hp[0], h1 = hp[1];
    float hv2[CH] = {h0.x,h0.y,h0.z,h0.w,h1.x,h1.y,h1.z,h1.w};
    float dn = dinv[node];
    #pragma unroll
    for(int c=0;c<CH;c++){
      float sv = (float)su.ss[c] * I16INV;
      float r = hv2[c] + convb[l*CH + c] + dn*(av[c] + sv);
      vv[c] = fmaxf(r, 0.f);
    }
    float4* hw4 = (float4*)(h + (size_t)node*CH);
    hw4[0] = make_float4(vv[0],vv[1],vv[2],vv[3]);
    hw4[1] = make_float4(vv[4],vv[5],vv[6],vv[7]);
  }
  // next-layer BN stats (multi-copy atomics: copy = b & 15)
  float s[CH], q[CH];
  #pragma unroll
  for(int c=0;c<CH;c++){ s[c]=vv[c]; q[c]=vv[c]*vv[c]; }
  #pragma unroll
  for(int off=32; off>0; off>>=1){
    #pragma unroll
    for(int c=0;c<CH;c++){ s[c]+=__shfl_down(s[c],off); q[c]+=__shfl_down(q[c],off); }
  }
  __shared__ float ls[8][2*CH];
  int wave = t>>6, lane = t&63;
  if(lane==0){
    #pragma unroll
    for(int c=0;c<CH;c++){ ls[wave][c]=s[c]; ls[wave][CH+c]=q[c]; }
  }
  __syncthreads();
  if(t < 2*CH){
    float tot = 0.f;
    #pragma unroll
    for(int w=0; w<8; w++) tot += ls[w][t];
    unsafeAtomicAdd(&stats_next[(t*SCOP + (b & (SCOP-1)))*SPAD], tot);
  }
}

// ---------------- entries: u = xe@W1, v = xe@W2 + hb ----------------
__global__ __launch_bounds__(256) void k_uv(const int* __restrict__ entry, const float* __restrict__ h,
                                            const float* __restrict__ hw, const float* __restrict__ hb,
                                            float* __restrict__ u, float* __restrict__ v){
  __shared__ float w[2*CH*HID];
  __shared__ float b[HID];
  for(int t=threadIdx.x; t<2*CH*HID; t+=256) w[t]=hw[t];
  if(threadIdx.x<HID) b[threadIdx.x]=hb[threadIdx.x];
  __syncthreads();
  int k = blockIdx.x*blockDim.x + threadIdx.x;
  if(k >= NENT) return;
  int node = entry[k];
  const float4* hp = (const float4*)(h + (size_t)node*CH);
  float4 a = hp[0], b4 = hp[1];
  float xe[CH] = {a.x,a.y,a.z,a.w,b4.x,b4.y,b4.z,b4.w};
  #pragma unroll 4
  for(int c=0;c<HID;c++){
    float uu = 0.f, vv = b[c];
    #pragma unroll
    for(int ci=0;ci<CH;ci++){
      uu += xe[ci]*w[ci*HID+c];
      vv += xe[ci]*w[(CH+ci)*HID+c];
    }
    u[(size_t)k*HID+c] = uu;
    v[(size_t)k*HID+c] = vv;
  }
}

// ---------------- pairwise scorer ----------------
__global__ __launch_bounds__(256) void k_pair(const float* __restrict__ u, const float* __restrict__ v,
                                              const float* __restrict__ ow, const float* __restrict__ ob,
                                              float* __restrict__ out){
  __shared__ float us[16][HID+1];
  __shared__ float vs[64][HID+1];
  __shared__ float wo[HID];
  int tid = threadIdx.x;
  int jb = blockIdx.x*64, ib = blockIdx.y*16;
  for(int t=tid; t<16*HID; t+=256) us[t>>5][t&31] = u[(size_t)(ib + (t>>5))*HID + (t&31)];
  for(int t=tid; t<64*HID; t+=256) vs[t>>5][t&31] = v[(size_t)(jb + (t>>5))*HID + (t&31)];
  if(tid<HID) wo[tid]=ow[tid];
  __syncthreads();
  int tx = tid&63, ty = tid>>6;
  float a0=0.f, a1=0.f, a2=0.f, a3=0.f;
  #pragma unroll
  for(int c=0;c<HID;c++){
    float vv = vs[tx][c];
    float w  = wo[c];
    a0 += fmaxf(us[ty   ][c]+vv, 0.f)*w;
    a1 += fmaxf(us[ty+4 ][c]+vv, 0.f)*w;
    a2 += fmaxf(us[ty+8 ][c]+vv, 0.f)*w;
    a3 += fmaxf(us[ty+12][c]+vv, 0.f)*w;
  }
  float o0 = ob[0];
  size_t base = (size_t)ib*2048 + jb + tx;
  out[base + (size_t)(ty   )*2048] = a0+o0;
  out[base + (size_t)(ty+4 )*2048] = a1+o0;
  out[base + (size_t)(ty+8 )*2048] = a2+o0;
  out[base + (size_t)(ty+12)*2048] = a3+o0;
}

extern "C" void kernel_launch(void* const* d_in, const int* in_sizes, int n_in,
                              void* d_out, int out_size, void* d_ws, size_t ws_size,
                              hipStream_t stream){
  const int*   x     = (const int*)d_in[0];
  const int*   ei    = (const int*)d_in[1];
  const int*   entry = (const int*)d_in[2];
  const float* emb   = (const float*)d_in[3];
  const float* gamma = (const float*)d_in[4];
  const float* beta  = (const float*)d_in[5];
  const float* convw = (const float*)d_in[6];
  const float* convb = (const float*)d_in[7];
  const float* hw    = (const float*)d_in[8];
  const float* hb    = (const float*)d_in[9];
  const float* ow    = (const float*)d_in[10];
  const float* ob    = (const float*)d_in[11];
  const int* srcp = ei;
  const int* dstp = ei + NEDGES;

  // workspace (~72 MB)
  char* ws = (char*)d_ws;
  size_t o = 0;
  auto alloc = [&](size_t bytes){ void* p = ws + o; o += (bytes + 255) & ~(size_t)255; return p; };
  int*      cnt    = (int*)     alloc((size_t)NCHUNK*NBUCK*4);   // 6.4 MB
  int*      total  = (int*)     alloc(NBUCK*4);
  int*      bbase  = (int*)     alloc((NBUCK+1)*4);
  unsigned* binned = (unsigned*)alloc((size_t)NEDGES*4);         // 25.6 MB (dst-bucket runs)
  unsigned* binned2= (unsigned*)alloc((size_t)NEDGES*4);         // 25.6 MB (src-sorted runs)
  float*    dinv   = (float*)   alloc(NNODES*4);
  float*    h      = (float*)   alloc((size_t)NNODES*CH*4);
  short*    hts    = (short*)   alloc((size_t)NNODES*CH*2);      // 3.2 MB int16 fixed-point
  float*    stats  = (float*)   alloc((size_t)(NCONV+1)*SSLOT*4);// 147 KB (multi-copy, line-padded)
  float*    ub     = (float*)   alloc((size_t)NENT*HID*4);
  float*    vb     = (float*)   alloc((size_t)NENT*HID*4);
  (void)ws_size; (void)in_sizes; (void)n_in; (void)out_size;

  // ---- deterministic CSR build + src-bin re-sort ----
  k_chist<<<NCHUNK, 256, 0, stream>>>(dstp, cnt, NEDGES);
  k_cscan<<<NBUCK, 256, 0, stream>>>(cnt, total);
  k_bscan<<<1, 1024, 0, stream>>>(total, bbase);
  k_bin  <<<NCHUNK, 1024, 0, stream>>>(srcp, dstp, cnt, total, bbase, binned, NEDGES);
  k_sub  <<<NBUCK, 512, 0, stream>>>(binned, bbase, binned2, dinv, NNODES);

  hipMemsetAsync(stats, 0, (size_t)(NCONV+1)*SSLOT*sizeof(float), stream);
  k_init_h<<<(NNODES+255)/256, 256, 0, stream>>>(x, emb, h, stats, NNODES);

  for(int l=0; l<NCONV; l++){
    k_ht  <<<(NNODES+255)/256, 256, 0, stream>>>(h, stats + (size_t)l*SSLOT, gamma, beta, convw,
                                                 dinv, hts, l, NNODES);
    k_push<<<NBUCK, 512, 0, stream>>>(binned2, bbase, hts, dinv, convb, h,
                                      stats + (size_t)(l+1)*SSLOT, l, NNODES);
  }

  k_uv<<<NENT/256, 256, 0, stream>>>(entry, h, hw, hb, ub, vb);
  dim3 pg(2048/64, 2048/16);
  k_pair<<<pg, 256, 0, stream>>>(ub, vb, ow, ob, (float*)d_out);
}

// Round 24
// 467.645 us; speedup vs baseline: 1.0102x; 1.0102x over previous
//
#include <hip/hip_runtime.h>
#include <hip/hip_fp16.h>

#define NNODES 200000
#define NEDGES 6400000
#define NENT   2048
#define CH     8
#define HID    32
#define NCONV  8
#define BN_EPS 1e-5f

#define BSZ    196                                  // nodes per dst-bucket
#define NBUCK  1024                                 // 1024 buckets -> exactly 4 blocks/CU
#define SRCB   391                                  // src bins (src>>9)
#define CHUNK  4096
#define NCHUNK ((NEDGES + CHUNK - 1) / CHUNK)       // 1563
#define SPAD   16                                   // one 64B line per stat-copy
#define SCOP   16                                   // stat copies (bounds same-line atomic serialization)
#define SUBCAP 8192                                 // staged edges per bucket (32 KB; run ~6272)
#define ESTG   512                                  // k_push edge stage size (128 groups x 4 edges)

#define I16SCALE  2048.0f                           // 2^11 fixed-point scale
#define I16INV    (1.0f/2048.0f)
#define BIAS      32768                             // uint16 bias (carry-free packed sums)

// stats slot layout: [stat t (0..15)][copy c (0..15)] each on its own 64B line
#define SSLOT  (2*CH*SCOP*SPAD)                     // floats per layer slot (4096)

__device__ __forceinline__ int bucket_of(int d){ return (int)((unsigned)d / 196u); }

// bijective XCD-chunked swizzle (m204 form): consecutive work-ids land on one XCD
__device__ __forceinline__ int xcd_swz(int bid, int nwg){
  int xcd = bid & 7, idx = bid >> 3;
  int q = nwg >> 3, r = nwg & 7;
  return (xcd < r ? xcd*(q+1) : r*(q+1) + (xcd-r)*q) + idx;
}

// ---------------- phase A: per-chunk bucket histogram ----------------
__global__ __launch_bounds__(256) void k_chist(const int* __restrict__ dst, int* __restrict__ cnt, int E){
  __shared__ int hist[NBUCK];
  for(int t=threadIdx.x; t<NBUCK; t+=256) hist[t]=0;
  __syncthreads();
  int e0 = blockIdx.x*CHUNK;
  int n = min(CHUNK, E-e0);
  for(int i=threadIdx.x; i<n; i+=256) atomicAdd(&hist[bucket_of(dst[e0+i])], 1);
  __syncthreads();
  for(int t=threadIdx.x; t<NBUCK; t+=256) cnt[(size_t)blockIdx.x*NBUCK + t] = hist[t];
}

// ---------------- phase B1: per-bucket exclusive scan over chunks (XCD-swizzled) ----------------
__global__ __launch_bounds__(256) void k_cscan(int* __restrict__ cnt, int* __restrict__ total){
  int b = xcd_swz(blockIdx.x, NBUCK);     // adjacent buckets on same XCD -> shared lines merge
  __shared__ int sd[256];
  int carry = 0;
  for(int base=0; base<NCHUNK; base+=256){
    int c = base + threadIdx.x;
    int v = (c<NCHUNK) ? cnt[(size_t)c*NBUCK + b] : 0;
    sd[threadIdx.x] = v; __syncthreads();
    #pragma unroll
    for(int o=1; o<256; o<<=1){
      int x = (threadIdx.x>=o) ? sd[threadIdx.x-o] : 0;
      __syncthreads();
      sd[threadIdx.x] += x;
      __syncthreads();
    }
    if(c<NCHUNK) cnt[(size_t)c*NBUCK + b] = carry + sd[threadIdx.x] - v;  // exclusive
    carry += sd[255];
    __syncthreads();
  }
  if(threadIdx.x==0) total[b] = carry;
}

// ---------------- phase B2: bucket base scan (1024 bins, 1024 threads) ----------------
__global__ __launch_bounds__(1024) void k_bscan(const int* __restrict__ total, int* __restrict__ bbase){
  __shared__ int sd[1024];
  int t = threadIdx.x;
  int v = total[t];
  sd[t] = v; __syncthreads();
  #pragma unroll
  for(int o=1; o<1024; o<<=1){
    int x = (t>=o) ? sd[t-o] : 0;
    __syncthreads();
    sd[t] += x;
    __syncthreads();
  }
  bbase[t] = sd[t] - v;
  if(t==1023) bbase[NBUCK] = sd[1023];   // == NEDGES
}

// ---------------- phase C: LDS counting-sort scatter into bucket runs ----------------
// packed edge = (dst_local<<18) | src   (src<2^18, dst_local<196)
__global__ __launch_bounds__(1024) void k_bin(const int* __restrict__ src, const int* __restrict__ dst,
                                              const int* __restrict__ cnt, const int* __restrict__ total,
                                              const int* __restrict__ bbase,
                                              unsigned int* __restrict__ binned, int E){
  __shared__ int excl[NBUCK], cur[NBUCK], base[NBUCK];
  __shared__ unsigned int pin[CHUNK];
  __shared__ unsigned short bk_in[CHUNK];
  __shared__ unsigned int sorted[CHUNK];
  __shared__ unsigned short sbkt[CHUNK];
  __shared__ int sd[1024];
  int c = xcd_swz(blockIdx.x, NCHUNK);
  int e0 = c*CHUNK, n = min(CHUNK, E-e0);
  int t = threadIdx.x;
  for(int i=t; i<n; i+=1024){
    int s = src[e0+i], d = dst[e0+i];
    int b = bucket_of(d);
    pin[i]   = ((unsigned)(d - b*BSZ)<<18) | (unsigned)s;
    bk_in[i] = (unsigned short)b;
  }
  int h0 = cnt[(size_t)c*NBUCK + t];
  int h1 = (c+1 < NCHUNK) ? cnt[(size_t)(c+1)*NBUCK + t] : total[t];
  int hv = h1 - h0;                        // this chunk's count for bucket t
  sd[t] = hv; __syncthreads();
  #pragma unroll
  for(int o=1; o<1024; o<<=1){
    int x = (t>=o) ? sd[t-o] : 0;
    __syncthreads();
    sd[t] += x;
    __syncthreads();
  }
  {
    int ex = sd[t] - hv;
    excl[t] = ex; cur[t] = ex;
    base[t] = bbase[t] + h0;
  }
  __syncthreads();
  for(int i=t; i<n; i+=1024){
    int b = bk_in[i];
    int slot = atomicAdd(&cur[b], 1);
    sorted[slot] = pin[i];
    sbkt[slot]   = (unsigned short)b;
  }
  __syncthreads();
  for(int i=t; i<n; i+=1024){
    int b = sbkt[i];
    binned[ base[b] + (i - excl[b]) ] = sorted[i];   // contiguous runs per bucket
  }
}

// ---------------- phase D: per-bucket SRC-BIN sort, LDS-staged coalesced output ----------------
__global__ __launch_bounds__(512) void k_sub(const unsigned int* __restrict__ binned,
                                             const int* __restrict__ bbase,
                                             unsigned int* __restrict__ binned2,
                                             float* __restrict__ dinv, int N){
  __shared__ int hd[BSZ];        // dst_local degree histogram
  __shared__ int hs[SRCB];       // src-bin histogram
  __shared__ int cur[SRCB];
  __shared__ int sd[512];
  __shared__ unsigned int stage[SUBCAP];   // 32 KB
  int b = blockIdx.x;
  int t = threadIdx.x;
  if(t < BSZ)  hd[t] = 0;
  if(t < SRCB) hs[t] = 0;
  __syncthreads();
  int s0 = bbase[b], s1 = bbase[b+1];
  for(int i=s0+t; i<s1; i+=512){
    unsigned p = binned[i];
    atomicAdd(&hd[p>>18], 1);
    atomicAdd(&hs[(p & 0x3FFFF)>>9], 1);
  }
  __syncthreads();
  if(t < BSZ){
    int node = b*BSZ + t;
    if(node < N) dinv[node] = 1.0f / sqrtf((float)hd[t] + 1.0f);
  }
  int hv = (t<SRCB) ? hs[t] : 0;
  sd[t] = hv; __syncthreads();
  #pragma unroll
  for(int o=1; o<512; o<<=1){
    int x = (t>=o) ? sd[t-o] : 0;
    __syncthreads();
    sd[t] += x;
    __syncthreads();
  }
  if(t<SRCB) cur[t] = sd[t] - hv;          // stage-relative
  __syncthreads();
  int len = s1 - s0;
  if(len <= SUBCAP){
    for(int i=s0+t; i<s1; i+=512){
      unsigned p = binned[i];
      int slot = atomicAdd(&cur[(p & 0x3FFFF)>>9], 1);
      stage[slot] = p;
    }
    __syncthreads();
    for(int i=t; i<len; i+=512) binned2[s0 + i] = stage[i];   // coalesced
  } else {                                 // degenerate fallback: direct scatter
    for(int i=s0+t; i<s1; i+=512){
      unsigned p = binned[i];
      int slot = atomicAdd(&cur[(p & 0x3FFFF)>>9], 1);
      binned2[s0 + slot] = p;
    }
  }
}

// ---------------- h init: embedding gather + stats[0] (multi-copy fp32 atomics) ----------------
__global__ __launch_bounds__(256) void k_init_h(const int* __restrict__ x, const float* __restrict__ emb,
                                                float* __restrict__ h, float* __restrict__ stats0, int N){
  int i = blockIdx.x*256 + threadIdx.x;
  float v[CH];
  #pragma unroll
  for(int c=0;c<CH;c++) v[c]=0.f;
  if(i < N){
    int tt = x[i];
    const float4* ep = (const float4*)(emb + (size_t)tt*CH);
    float4 a = ep[0], b = ep[1];
    float4* hp = (float4*)(h + (size_t)i*CH);
    hp[0] = a; hp[1] = b;
    v[0]=a.x; v[1]=a.y; v[2]=a.z; v[3]=a.w; v[4]=b.x; v[5]=b.y; v[6]=b.z; v[7]=b.w;
  }
  float s[CH], q[CH];
  #pragma unroll
  for(int c=0;c<CH;c++){ s[c]=v[c]; q[c]=v[c]*v[c]; }
  #pragma unroll
  for(int off=32; off>0; off>>=1){
    #pragma unroll
    for(int c=0;c<CH;c++){ s[c]+=__shfl_down(s[c],off); q[c]+=__shfl_down(q[c],off); }
  }
  __shared__ float ls[4][2*CH];
  int wave = threadIdx.x>>6, lane = threadIdx.x&63;
  if(lane==0){
    #pragma unroll
    for(int c=0;c<CH;c++){ ls[wave][c]=s[c]; ls[wave][CH+c]=q[c]; }
  }
  __syncthreads();
  if(threadIdx.x < 2*CH){
    float tsum = ls[0][threadIdx.x]+ls[1][threadIdx.x]+ls[2][threadIdx.x]+ls[3][threadIdx.x];
    unsafeAtomicAdd(&stats0[(threadIdx.x*SCOP + (blockIdx.x & (SCOP-1)))*SPAD], tsum);
  }
}

// ---------------- per-node transform: fold BN, hts32 = packed biased uint16 pairs ----------------
// channel pair j stored as uint32: (u16)(v[2j]+BIAS) | (u16)(v[2j+1]+BIAS)<<16
__global__ __launch_bounds__(256) void k_ht(const float* __restrict__ h, const float* __restrict__ stats_l,
                                            const float* __restrict__ gamma, const float* __restrict__ beta,
                                            const float* __restrict__ convw,
                                            const float* __restrict__ dinv,
                                            unsigned* __restrict__ hts32, int l, int N){
  __shared__ float A[CH*CH], c0[CH], sA[CH], sT[CH];
  int t = threadIdx.x;
  if(t < CH){
    float mu = 0.f, ex2 = 0.f;
    #pragma unroll
    for(int c=0;c<SCOP;c++){
      mu  += stats_l[((t   )*SCOP + c)*SPAD];
      ex2 += stats_l[((CH+t)*SCOP + c)*SPAD];
    }
    const float invN = 1.0f / (float)NNODES;
    mu *= invN; ex2 *= invN;
    float var = ex2 - mu*mu;
    float r   = 1.0f / sqrtf(var + BN_EPS);
    float sc  = r * gamma[l*CH+t];
    sA[t] = sc;
    sT[t] = beta[l*CH+t] - mu*sc;
  }
  __syncthreads();
  if(t < CH*CH){
    int ci = t>>3, co = t&7;
    A[t] = sA[ci] * convw[(l*CH+ci)*CH+co];
  }
  if(t < CH){
    float a = 0.f;
    #pragma unroll
    for(int ci=0;ci<CH;ci++) a += sT[ci]*convw[(l*CH+ci)*CH+t];
    c0[t] = a;
  }
  __syncthreads();
  int i = blockIdx.x*blockDim.x + threadIdx.x;
  if(i >= N) return;
  const float4* hp = (const float4*)(h + (size_t)i*CH);
  float4 a = hp[0], b = hp[1];
  float v[CH] = {a.x,a.y,a.z,a.w,b.x,b.y,b.z,b.w};
  float o[CH];
  #pragma unroll
  for(int co=0;co<CH;co++) o[co]=c0[co];
  #pragma unroll
  for(int ci=0;ci<CH;ci++){
    float vv = v[ci];
    #pragma unroll
    for(int co=0;co<CH;co++) o[co] += vv*A[ci*CH+co];
  }
  float dn = dinv[i] * I16SCALE;
  unsigned pk[4];
  #pragma unroll
  for(int j=0;j<4;j++){
    float f0 = fminf(fmaxf(o[2*j  ]*dn, -32767.f), 32767.f);
    float f1 = fminf(fmaxf(o[2*j+1]*dn, -32767.f), 32767.f);
    unsigned u0 = (unsigned)(__float2int_rn(f0) + BIAS);
    unsigned u1 = (unsigned)(__float2int_rn(f1) + BIAS);
    pk[j] = u0 | (u1 << 16);
  }
  *(uint4*)(hts32 + (size_t)i*4) = make_uint4(pk[0],pk[1],pk[2],pk[3]);
}

// ---------------- src-sorted bucket push + FUSED finalize (u64 packed atomics) ----------------
// 1024 blocks (4/CU balanced), 512 threads = 128 groups x 4 lanes.
// Lane owns a CHANNEL PAIR: gathers one uint32 (2 biased u16), expands to u64
// (lo | hi<<32), one native ds_add_u64 per edge-lane -> LDS instr count halves.
__global__ __launch_bounds__(512) void k_push(const unsigned int* __restrict__ binned2,
                                              const int* __restrict__ bbase,
                                              const unsigned* __restrict__ hts32,
                                              const float* __restrict__ dinv,
                                              const float* __restrict__ convb,
                                              float* __restrict__ h, float* __restrict__ stats_next,
                                              int l, int N){
  __shared__ unsigned long long acc[BSZ*4];   // 6.3 KB packed pairs
  __shared__ unsigned est[ESTG];              // 2 KB edge stage
  int b = blockIdx.x, t = threadIdx.x;
  for(int i=t; i<BSZ*4; i+=512) acc[i] = 0ull;
  __syncthreads();
  int s0 = bbase[b], s1 = bbase[b+1];
  int lane4 = t & 3;
  int g = t >> 2;                          // 0..127
  int e0 = g*4;
  for(int off = s0; off < s1; off += ESTG){
    int n = min(ESTG, s1 - off);
    if(t < n) est[t] = binned2[off + t];   // coalesced
    __syncthreads();
    int m = n - e0;                        // edges for this group (<=4)
    if(m >= 4){
      unsigned p0=est[e0], p1=est[e0+1], p2=est[e0+2], p3=est[e0+3];
      unsigned w0 = hts32[(size_t)(p0 & 0x3FFFF)*4 + lane4];
      unsigned w1 = hts32[(size_t)(p1 & 0x3FFFF)*4 + lane4];
      unsigned w2 = hts32[(size_t)(p2 & 0x3FFFF)*4 + lane4];
      unsigned w3 = hts32[(size_t)(p3 & 0x3FFFF)*4 + lane4];
      unsigned long long v0 = (unsigned long long)(w0 & 0xFFFFu) | ((unsigned long long)(w0 >> 16) << 32);
      unsigned long long v1 = (unsigned long long)(w1 & 0xFFFFu) | ((unsigned long long)(w1 >> 16) << 32);
      unsigned long long v2 = (unsigned long long)(w2 & 0xFFFFu) | ((unsigned long long)(w2 >> 16) << 32);
      unsigned long long v3 = (unsigned long long)(w3 & 0xFFFFu) | ((unsigned long long)(w3 >> 16) << 32);
      atomicAdd(&acc[(p0>>18)*4 + lane4], v0);
      atomicAdd(&acc[(p1>>18)*4 + lane4], v1);
      atomicAdd(&acc[(p2>>18)*4 + lane4], v2);
      atomicAdd(&acc[(p3>>18)*4 + lane4], v3);
    } else if(m > 0){
      for(int i=0; i<m; i++){
        unsigned p = est[e0+i];
        unsigned w = hts32[(size_t)(p & 0x3FFFF)*4 + lane4];
        unsigned long long v = (unsigned long long)(w & 0xFFFFu) | ((unsigned long long)(w >> 16) << 32);
        atomicAdd(&acc[(p>>18)*4 + lane4], v);
      }
    }
    __syncthreads();
  }
  // epilogue: thread t<BSZ owns node b*BSZ+t (this block exclusively owns these dsts)
  float vv[CH];
  #pragma unroll
  for(int c=0;c<CH;c++) vv[c]=0.f;
  int node = b*BSZ + t;
  if(t < BSZ && node < N){
    float dn = dinv[node];
    int deg = (int)roundf(1.0f/(dn*dn)) - 1;
    int bias = deg * BIAS;
    float av[CH];
    #pragma unroll
    for(int j=0;j<4;j++){
      unsigned long long a = acc[t*4 + j];
      int lo = (int)(unsigned)(a & 0xFFFFFFFFull) - bias;
      int hi = (int)(unsigned)(a >> 32)           - bias;
      av[2*j]   = (float)lo * I16INV;
      av[2*j+1] = (float)hi * I16INV;
    }
    uint4 su = *(const uint4*)(hts32 + (size_t)node*4);    // self loop (biased pairs)
    unsigned sw[4] = {su.x, su.y, su.z, su.w};
    const float4* hp = (const float4*)(h + (size_t)node*CH);
    float4 h0 = hp[0], h1 = hp[1];
    float hv2[CH] = {h0.x,h0.y,h0.z,h0.w,h1.x,h1.y,h1.z,h1.w};
    #pragma unroll
    for(int j=0;j<4;j++){
      float sv0 = (float)((int)(sw[j] & 0xFFFFu) - BIAS) * I16INV;
      float sv1 = (float)((int)(sw[j] >> 16)     - BIAS) * I16INV;
      float r0 = hv2[2*j]   + convb[l*CH + 2*j]   + dn*(av[2*j]   + sv0);
      float r1 = hv2[2*j+1] + convb[l*CH + 2*j+1] + dn*(av[2*j+1] + sv1);
      vv[2*j]   = fmaxf(r0, 0.f);
      vv[2*j+1] = fmaxf(r1, 0.f);
    }
    float4* hw4 = (float4*)(h + (size_t)node*CH);
    hw4[0] = make_float4(vv[0],vv[1],vv[2],vv[3]);
    hw4[1] = make_float4(vv[4],vv[5],vv[6],vv[7]);
  }
  // next-layer BN stats (multi-copy atomics: copy = b & 15)
  float s[CH], q[CH];
  #pragma unroll
  for(int c=0;c<CH;c++){ s[c]=vv[c]; q[c]=vv[c]*vv[c]; }
  #pragma unroll
  for(int off=32; off>0; off>>=1){
    #pragma unroll
    for(int c=0;c<CH;c++){ s[c]+=__shfl_down(s[c],off); q[c]+=__shfl_down(q[c],off); }
  }
  __shared__ float ls[8][2*CH];
  int wave = t>>6, lane = t&63;
  if(lane==0){
    #pragma unroll
    for(int c=0;c<CH;c++){ ls[wave][c]=s[c]; ls[wave][CH+c]=q[c]; }
  }
  __syncthreads();
  if(t < 2*CH){
    float tot = 0.f;
    #pragma unroll
    for(int w=0; w<8; w++) tot += ls[w][t];
    unsafeAtomicAdd(&stats_next[(t*SCOP + (b & (SCOP-1)))*SPAD], tot);
  }
}

// ---------------- entries: u = xe@W1, v = xe@W2 + hb ----------------
__global__ __launch_bounds__(256) void k_uv(const int* __restrict__ entry, const float* __restrict__ h,
                                            const float* __restrict__ hw, const float* __restrict__ hb,
                                            float* __restrict__ u, float* __restrict__ v){
  __shared__ float w[2*CH*HID];
  __shared__ float b[HID];
  for(int t=threadIdx.x; t<2*CH*HID; t+=256) w[t]=hw[t];
  if(threadIdx.x<HID) b[threadIdx.x]=hb[threadIdx.x];
  __syncthreads();
  int k = blockIdx.x*blockDim.x + threadIdx.x;
  if(k >= NENT) return;
  int node = entry[k];
  const float4* hp = (const float4*)(h + (size_t)node*CH);
  float4 a = hp[0], b4 = hp[1];
  float xe[CH] = {a.x,a.y,a.z,a.w,b4.x,b4.y,b4.z,b4.w};
  #pragma unroll 4
  for(int c=0;c<HID;c++){
    float uu = 0.f, vv = b[c];
    #pragma unroll
    for(int ci=0;ci<CH;ci++){
      uu += xe[ci]*w[ci*HID+c];
      vv += xe[ci]*w[(CH+ci)*HID+c];
    }
    u[(size_t)k*HID+c] = uu;
    v[(size_t)k*HID+c] = vv;
  }
}

// ---------------- pairwise scorer ----------------
__global__ __launch_bounds__(256) void k_pair(const float* __restrict__ u, const float* __restrict__ v,
                                              const float* __restrict__ ow, const float* __restrict__ ob,
                                              float* __restrict__ out){
  __shared__ float us[16][HID+1];
  __shared__ float vs[64][HID+1];
  __shared__ float wo[HID];
  int tid = threadIdx.x;
  int jb = blockIdx.x*64, ib = blockIdx.y*16;
  for(int t=tid; t<16*HID; t+=256) us[t>>5][t&31] = u[(size_t)(ib + (t>>5))*HID + (t&31)];
  for(int t=tid; t<64*HID; t+=256) vs[t>>5][t&31] = v[(size_t)(jb + (t>>5))*HID + (t&31)];
  if(tid<HID) wo[tid]=ow[tid];
  __syncthreads();
  int tx = tid&63, ty = tid>>6;
  float a0=0.f, a1=0.f, a2=0.f, a3=0.f;
  #pragma unroll
  for(int c=0;c<HID;c++){
    float vv = vs[tx][c];
    float w  = wo[c];
    a0 += fmaxf(us[ty   ][c]+vv, 0.f)*w;
    a1 += fmaxf(us[ty+4 ][c]+vv, 0.f)*w;
    a2 += fmaxf(us[ty+8 ][c]+vv, 0.f)*w;
    a3 += fmaxf(us[ty+12][c]+vv, 0.f)*w;
  }
  float o0 = ob[0];
  size_t base = (size_t)ib*2048 + jb + tx;
  out[base + (size_t)(ty   )*2048] = a0+o0;
  out[base + (size_t)(ty+4 )*2048] = a1+o0;
  out[base + (size_t)(ty+8 )*2048] = a2+o0;
  out[base + (size_t)(ty+12)*2048] = a3+o0;
}

extern "C" void kernel_launch(void* const* d_in, const int* in_sizes, int n_in,
                              void* d_out, int out_size, void* d_ws, size_t ws_size,
                              hipStream_t stream){
  const int*   x     = (const int*)d_in[0];
  const int*   ei    = (const int*)d_in[1];
  const int*   entry = (const int*)d_in[2];
  const float* emb   = (const float*)d_in[3];
  const float* gamma = (const float*)d_in[4];
  const float* beta  = (const float*)d_in[5];
  const float* convw = (const float*)d_in[6];
  const float* convb = (const float*)d_in[7];
  const float* hw    = (const float*)d_in[8];
  const float* hb    = (const float*)d_in[9];
  const float* ow    = (const float*)d_in[10];
  const float* ob    = (const float*)d_in[11];
  const int* srcp = ei;
  const int* dstp = ei + NEDGES;

  // workspace (~72 MB)
  char* ws = (char*)d_ws;
  size_t o = 0;
  auto alloc = [&](size_t bytes){ void* p = ws + o; o += (bytes + 255) & ~(size_t)255; return p; };
  int*      cnt    = (int*)     alloc((size_t)NCHUNK*NBUCK*4);   // 6.4 MB
  int*      total  = (int*)     alloc(NBUCK*4);
  int*      bbase  = (int*)     alloc((NBUCK+1)*4);
  unsigned* binned = (unsigned*)alloc((size_t)NEDGES*4);         // 25.6 MB (dst-bucket runs)
  unsigned* binned2= (unsigned*)alloc((size_t)NEDGES*4);         // 25.6 MB (src-sorted runs)
  float*    dinv   = (float*)   alloc(NNODES*4);
  float*    h      = (float*)   alloc((size_t)NNODES*CH*4);
  unsigned* hts32  = (unsigned*)alloc((size_t)NNODES*4*4);       // 3.2 MB packed biased pairs
  float*    stats  = (float*)   alloc((size_t)(NCONV+1)*SSLOT*4);// 147 KB (multi-copy, line-padded)
  float*    ub     = (float*)   alloc((size_t)NENT*HID*4);
  float*    vb     = (float*)   alloc((size_t)NENT*HID*4);
  (void)ws_size; (void)in_sizes; (void)n_in; (void)out_size;

  // ---- deterministic CSR build + src-bin re-sort ----
  k_chist<<<NCHUNK, 256, 0, stream>>>(dstp, cnt, NEDGES);
  k_cscan<<<NBUCK, 256, 0, stream>>>(cnt, total);
  k_bscan<<<1, 1024, 0, stream>>>(total, bbase);
  k_bin  <<<NCHUNK, 1024, 0, stream>>>(srcp, dstp, cnt, total, bbase, binned, NEDGES);
  k_sub  <<<NBUCK, 512, 0, stream>>>(binned, bbase, binned2, dinv, NNODES);

  hipMemsetAsync(stats, 0, (size_t)(NCONV+1)*SSLOT*sizeof(float), stream);
  k_init_h<<<(NNODES+255)/256, 256, 0, stream>>>(x, emb, h, stats, NNODES);

  for(int l=0; l<NCONV; l++){
    k_ht  <<<(NNODES+255)/256, 256, 0, stream>>>(h, stats + (size_t)l*SSLOT, gamma, beta, convw,
                                                 dinv, hts32, l, NNODES);
    k_push<<<NBUCK, 512, 0, stream>>>(binned2, bbase, hts32, dinv, convb, h,
                                      stats + (size_t)(l+1)*SSLOT, l, NNODES);
  }

  k_uv<<<NENT/256, 256, 0, stream>>>(entry, h, hw, hb, ub, vb);
  dim3 pg(2048/64, 2048/16);
  k_pair<<<pg, 256, 0, stream>>>(ub, vb, ow, ob, (float*)d_out);
}